// Round 6
// baseline (101.452 us; speedup 1.0000x reference)
//
#include <hip/hip_runtime.h>
#include <math.h>

// Problem constants
#define BB 8
#define CC 3
#define DD 24
#define HH 128
#define WW 128
#define HW (HH * WW)
#define OCC 16
#define DOUT 22   // 24 - 2
#define HOUT 126
#define WOUT 126

// Kernel 1: transpose weights [oc][tap] -> [tap][oc] into d_ws so each tap's
// 16 oc-weights are contiguous (64 B) -> wave-uniform float4 loads become
// s_load_dwordx4/x16 and weights live in SGPRs (v_fmac_f32 takes 1 SGPR op).
__global__ void wtrans_kernel(const float* __restrict__ wt,
                              float* __restrict__ wT) {
  const int i = blockIdx.x * 256 + threadIdx.x;
  if (i < 81 * 16) {
    const int tap = i >> 4;
    const int oc = i & 15;
    wT[i] = wt[oc * 81 + tap];
  }
}

// Kernel 2: 512-thread blocks = 8 waves; wave g handles dz sub-range
// ({3,3,3,3,3,3,2,2} of the 22 depths) -> 8064 waves total, up to 4
// blocks/CU = 32 waves/CU for latency hiding (rounds 4/5 were TLP-starved
// at ~11 waves/CU). Each lane computes 2 adjacent output columns
// (w0 = 2*lane) for all 16 channels. Weights read at wave-uniform addresses
// in 3-tap (48-float) windows -> SGPRs; zero DS traffic in the main loop.
// Partial mins combined via a two-stage LDS tree (4 reused buffers, 31.5 KB
// so 4 blocks fit in 160 KB LDS); softmax + stores by wave 0.
__global__ __launch_bounds__(512) void conv_min_softmax_kernel(
    const float* __restrict__ x, const float* __restrict__ wT,
    float* __restrict__ out) {
  __shared__ float sm[4][OCC][WOUT];  // two-stage combine buffers

  const int tid = threadIdx.x;
  const int lane = tid & 63;
  const int g = tid >> 6;  // wave id 0..7
  const int h = blockIdx.y;
  const int b = blockIdx.z;
  const bool active = (lane < 63);          // 63 lanes cover w0 = 0..124
  const int w0 = 2 * (active ? lane : 62);  // clamp inactive lane's addresses

  // dz ranges per wave: waves 0..5 -> 3 dz each (start 3g), waves 6,7 -> 2 dz
  const int dz0 = (g < 6) ? 3 * g : 18 + 2 * (g - 6);
  const int ndz = (g < 6) ? 3 : 2;

  // Pointer at (b, c=0, depth=dz0, h, w0)
  const float* xd =
      x + (((size_t)b * CC * DD + dz0) * HH + h) * (size_t)WW + w0;

  float mn0[OCC], mn1[OCC];
#pragma unroll
  for (int oc = 0; oc < OCC; ++oc) { mn0[oc] = INFINITY; mn1[oc] = INFINITY; }

#pragma clang loop unroll(disable)
  for (int i = 0; i < ndz; ++i) {
    float y0[OCC], y1[OCC];
#pragma unroll
    for (int oc = 0; oc < OCC; ++oc) { y0[oc] = 0.f; y1[oc] = 0.f; }

    const float* ps = xd;  // slice (c=0, kd=0)
#pragma clang loop unroll(disable)
    for (int s = 0; s < 9; ++s) {  // slice = (c, kd)
      const float* wslice = wT + s * 144;
#pragma clang loop unroll(disable)
      for (int tg = 0; tg < 3; ++tg) {  // tg = kh row; 3 taps, 48 weights
        // 4 x-values of this input row (covers both output columns, kw 0..2)
        const float* row = ps + tg * WW;
        const float2 a = *reinterpret_cast<const float2*>(row);
        const float2 c2 = *reinterpret_cast<const float2*>(row + 2);
        const float xq0 = a.x, xq1 = a.y, xq2 = c2.x, xq3 = c2.y;

        const float* wp = wslice + tg * 48;
#pragma unroll
        for (int kw = 0; kw < 3; ++kw) {
          const float4 wA = *reinterpret_cast<const float4*>(wp + kw * 16 + 0);
          const float4 wB = *reinterpret_cast<const float4*>(wp + kw * 16 + 4);
          const float4 wC = *reinterpret_cast<const float4*>(wp + kw * 16 + 8);
          const float4 wD = *reinterpret_cast<const float4*>(wp + kw * 16 + 12);
          const float xa = (kw == 0) ? xq0 : (kw == 1) ? xq1 : xq2;
          const float xb2 = (kw == 0) ? xq1 : (kw == 1) ? xq2 : xq3;
          y0[0]  = fmaf(xa, wA.x, y0[0]);   y1[0]  = fmaf(xb2, wA.x, y1[0]);
          y0[1]  = fmaf(xa, wA.y, y0[1]);   y1[1]  = fmaf(xb2, wA.y, y1[1]);
          y0[2]  = fmaf(xa, wA.z, y0[2]);   y1[2]  = fmaf(xb2, wA.z, y1[2]);
          y0[3]  = fmaf(xa, wA.w, y0[3]);   y1[3]  = fmaf(xb2, wA.w, y1[3]);
          y0[4]  = fmaf(xa, wB.x, y0[4]);   y1[4]  = fmaf(xb2, wB.x, y1[4]);
          y0[5]  = fmaf(xa, wB.y, y0[5]);   y1[5]  = fmaf(xb2, wB.y, y1[5]);
          y0[6]  = fmaf(xa, wB.z, y0[6]);   y1[6]  = fmaf(xb2, wB.z, y1[6]);
          y0[7]  = fmaf(xa, wB.w, y0[7]);   y1[7]  = fmaf(xb2, wB.w, y1[7]);
          y0[8]  = fmaf(xa, wC.x, y0[8]);   y1[8]  = fmaf(xb2, wC.x, y1[8]);
          y0[9]  = fmaf(xa, wC.y, y0[9]);   y1[9]  = fmaf(xb2, wC.y, y1[9]);
          y0[10] = fmaf(xa, wC.z, y0[10]);  y1[10] = fmaf(xb2, wC.z, y1[10]);
          y0[11] = fmaf(xa, wC.w, y0[11]);  y1[11] = fmaf(xb2, wC.w, y1[11]);
          y0[12] = fmaf(xa, wD.x, y0[12]);  y1[12] = fmaf(xb2, wD.x, y1[12]);
          y0[13] = fmaf(xa, wD.y, y0[13]);  y1[13] = fmaf(xb2, wD.y, y1[13]);
          y0[14] = fmaf(xa, wD.z, y0[14]);  y1[14] = fmaf(xb2, wD.z, y1[14]);
          y0[15] = fmaf(xa, wD.w, y0[15]);  y1[15] = fmaf(xb2, wD.w, y1[15]);
        }
      }
      // advance slice: kd step = HW; (c,2)->(c+1,0) step = (DD-2)*HW
      ps += (s == 2 || s == 5) ? (size_t)(DD - 2) * HW : (size_t)HW;
    }

#pragma unroll
    for (int oc = 0; oc < OCC; ++oc) {
      mn0[oc] = fminf(mn0[oc], y0[oc]);
      mn1[oc] = fminf(mn1[oc], y1[oc]);
    }
    xd += HW;  // next depth
  }

  // Stage 1: waves 4..7 publish partial mins into buffers 0..3.
  // Layout [oc][w] with lanes at w0=2*lane -> 2-way bank aliasing (free).
  if (g >= 4 && active) {
#pragma unroll
    for (int oc = 0; oc < OCC; ++oc) {
      sm[g - 4][oc][w0] = mn0[oc];
      sm[g - 4][oc][w0 + 1] = mn1[oc];
    }
  }
  __syncthreads();

  if (g < 4 && active) {
    // Wave g merges buffer g (each lane reads/writes only its own columns,
    // so the stage-2 reuse of buffers 1..3 below is hazard-free).
#pragma unroll
    for (int oc = 0; oc < OCC; ++oc) {
      mn0[oc] = fminf(mn0[oc], sm[g][oc][w0]);
      mn1[oc] = fminf(mn1[oc], sm[g][oc][w0 + 1]);
    }
    // Stage 2: waves 1..3 publish merged mins into buffers 1..3.
    if (g > 0) {
#pragma unroll
      for (int oc = 0; oc < OCC; ++oc) {
        sm[g][oc][w0] = mn0[oc];
        sm[g][oc][w0 + 1] = mn1[oc];
      }
    }
  }
  __syncthreads();

  if (g == 0 && active) {
#pragma unroll
    for (int oc = 0; oc < OCC; ++oc) {
      mn0[oc] = fminf(fminf(mn0[oc], sm[1][oc][w0]),
                      fminf(sm[2][oc][w0], sm[3][oc][w0]));
      mn1[oc] = fminf(fminf(mn1[oc], sm[1][oc][w0 + 1]),
                      fminf(sm[2][oc][w0 + 1], sm[3][oc][w0 + 1]));
    }
    float mx0 = mn0[0], mx1 = mn1[0];
#pragma unroll
    for (int oc = 1; oc < OCC; ++oc) {
      mx0 = fmaxf(mx0, mn0[oc]);
      mx1 = fmaxf(mx1, mn1[oc]);
    }
    float e0[OCC], e1[OCC];
    float s0 = 0.f, s1 = 0.f;
#pragma unroll
    for (int oc = 0; oc < OCC; ++oc) {
      e0[oc] = __expf(mn0[oc] - mx0); s0 += e0[oc];
      e1[oc] = __expf(mn1[oc] - mx1); s1 += e1[oc];
    }
    const float i0 = 1.f / s0;
    const float i1 = 1.f / s1;

    float* ob = out + ((size_t)b * OCC * HOUT + h) * (size_t)WOUT + w0;
    const size_t os = (size_t)HOUT * WOUT;
#pragma unroll
    for (int oc = 0; oc < OCC; ++oc) {
      float2 v;
      v.x = e0[oc] * i0;
      v.y = e1[oc] * i1;
      *reinterpret_cast<float2*>(ob + oc * os) = v;  // w0 even -> 8B aligned
    }
  }
}

extern "C" void kernel_launch(void* const* d_in, const int* in_sizes, int n_in,
                              void* d_out, int out_size, void* d_ws, size_t ws_size,
                              hipStream_t stream) {
  const float* x = (const float*)d_in[0];
  const float* wt = (const float*)d_in[1];
  float* out = (float*)d_out;
  float* wT = (float*)d_ws;  // 81*16 floats = 5184 B scratch

  wtrans_kernel<<<dim3(6), dim3(256), 0, stream>>>(wt, wT);

  dim3 grid(1, HOUT, BB);   // 1008 blocks
  dim3 block(512, 1, 1);    // 8 waves = 8 dz-groups, Wtile=2
  conv_min_softmax_kernel<<<grid, block, 0, stream>>>(x, wT, out);
}

// Round 7
// 92.843 us; speedup vs baseline: 1.0927x; 1.0927x over previous
//
#include <hip/hip_runtime.h>
#include <math.h>

// Problem constants
#define BB 8
#define CC 3
#define DD 24
#define HH 128
#define WW 128
#define HW (HH * WW)
#define OCC 16
#define DOUT 22   // 24 - 2
#define HOUT 126
#define WOUT 126

// Kernel 1: transpose weights [oc][tap] -> [tap][oc] into d_ws so each tap's
// 16 oc-weights are contiguous (64 B) -> wave-uniform float4 loads become
// s_load_dwordx4/x16 and weights live in SGPRs (v_fmac_f32 takes 1 SGPR op).
__global__ void wtrans_kernel(const float* __restrict__ wt,
                              float* __restrict__ wT) {
  const int i = blockIdx.x * 256 + threadIdx.x;
  if (i < 81 * 16) {
    const int tap = i >> 4;
    const int oc = i & 15;
    wT[i] = wt[oc * 81 + tap];
  }
}

// Kernel 2: 512-thread blocks = 8 waves; wave g handles dz sub-range
// ({3,3,3,3,3,3,2,2} of the 22 depths). Each lane computes 2 adjacent output
// columns (w0 = 2*lane) for all 16 channels; weights come from wave-uniform
// s_loads (SGPRs), partial mins merge via a 2-stage LDS tree, wave 0 does
// softmax + stores.
//
// ROUND 7 CHANGE: 1-D grid with b = wgid & 7 so each batch's 126 h-blocks
// all land on ONE XCD (round-robin id%8 -> XCD). x per batch = 4.7 MB ~= one
// XCD's 4 MB L2, so the 3x-in-h / 3x-in-dz row re-reads become L2 hits
// instead of HBM misses (round 6: 130 MB HBM fetch = L2 thrash = the stall).
__global__ __launch_bounds__(512) void conv_min_softmax_kernel(
    const float* __restrict__ x, const float* __restrict__ wT,
    float* __restrict__ out) {
  __shared__ float sm[4][OCC][WOUT];  // two-stage combine buffers

  const int tid = threadIdx.x;
  const int lane = tid & 63;
  const int g = tid >> 6;  // wave id 0..7
  const int wg = blockIdx.x;
  const int b = wg & 7;    // XCD selector: all h-blocks of batch b -> XCD b
  const int h = wg >> 3;   // 0..125, in dispatch order per XCD
  const bool active = (lane < 63);          // 63 lanes cover w0 = 0..124
  const int w0 = 2 * (active ? lane : 62);  // clamp inactive lane's addresses

  // dz ranges per wave: waves 0..5 -> 3 dz each (start 3g), waves 6,7 -> 2 dz
  const int dz0 = (g < 6) ? 3 * g : 18 + 2 * (g - 6);
  const int ndz = (g < 6) ? 3 : 2;

  // Pointer at (b, c=0, depth=dz0, h, w0)
  const float* xd =
      x + (((size_t)b * CC * DD + dz0) * HH + h) * (size_t)WW + w0;

  float mn0[OCC], mn1[OCC];
#pragma unroll
  for (int oc = 0; oc < OCC; ++oc) { mn0[oc] = INFINITY; mn1[oc] = INFINITY; }

#pragma clang loop unroll(disable)
  for (int i = 0; i < ndz; ++i) {
    float y0[OCC], y1[OCC];
#pragma unroll
    for (int oc = 0; oc < OCC; ++oc) { y0[oc] = 0.f; y1[oc] = 0.f; }

    const float* ps = xd;  // slice (c=0, kd=0)
#pragma clang loop unroll(disable)
    for (int s = 0; s < 9; ++s) {  // slice = (c, kd)
      const float* wslice = wT + s * 144;
#pragma clang loop unroll(disable)
      for (int tg = 0; tg < 3; ++tg) {  // tg = kh row; 3 taps, 48 weights
        // 4 x-values of this input row (covers both output columns, kw 0..2)
        const float* row = ps + tg * WW;
        const float2 a = *reinterpret_cast<const float2*>(row);
        const float2 c2 = *reinterpret_cast<const float2*>(row + 2);
        const float xq0 = a.x, xq1 = a.y, xq2 = c2.x, xq3 = c2.y;

        const float* wp = wslice + tg * 48;
#pragma unroll
        for (int kw = 0; kw < 3; ++kw) {
          const float4 wA = *reinterpret_cast<const float4*>(wp + kw * 16 + 0);
          const float4 wB = *reinterpret_cast<const float4*>(wp + kw * 16 + 4);
          const float4 wC = *reinterpret_cast<const float4*>(wp + kw * 16 + 8);
          const float4 wD = *reinterpret_cast<const float4*>(wp + kw * 16 + 12);
          const float xa = (kw == 0) ? xq0 : (kw == 1) ? xq1 : xq2;
          const float xb2 = (kw == 0) ? xq1 : (kw == 1) ? xq2 : xq3;
          y0[0]  = fmaf(xa, wA.x, y0[0]);   y1[0]  = fmaf(xb2, wA.x, y1[0]);
          y0[1]  = fmaf(xa, wA.y, y0[1]);   y1[1]  = fmaf(xb2, wA.y, y1[1]);
          y0[2]  = fmaf(xa, wA.z, y0[2]);   y1[2]  = fmaf(xb2, wA.z, y1[2]);
          y0[3]  = fmaf(xa, wA.w, y0[3]);   y1[3]  = fmaf(xb2, wA.w, y1[3]);
          y0[4]  = fmaf(xa, wB.x, y0[4]);   y1[4]  = fmaf(xb2, wB.x, y1[4]);
          y0[5]  = fmaf(xa, wB.y, y0[5]);   y1[5]  = fmaf(xb2, wB.y, y1[5]);
          y0[6]  = fmaf(xa, wB.z, y0[6]);   y1[6]  = fmaf(xb2, wB.z, y1[6]);
          y0[7]  = fmaf(xa, wB.w, y0[7]);   y1[7]  = fmaf(xb2, wB.w, y1[7]);
          y0[8]  = fmaf(xa, wC.x, y0[8]);   y1[8]  = fmaf(xb2, wC.x, y1[8]);
          y0[9]  = fmaf(xa, wC.y, y0[9]);   y1[9]  = fmaf(xb2, wC.y, y1[9]);
          y0[10] = fmaf(xa, wC.z, y0[10]);  y1[10] = fmaf(xb2, wC.z, y1[10]);
          y0[11] = fmaf(xa, wC.w, y0[11]);  y1[11] = fmaf(xb2, wC.w, y1[11]);
          y0[12] = fmaf(xa, wD.x, y0[12]);  y1[12] = fmaf(xb2, wD.x, y1[12]);
          y0[13] = fmaf(xa, wD.y, y0[13]);  y1[13] = fmaf(xb2, wD.y, y1[13]);
          y0[14] = fmaf(xa, wD.z, y0[14]);  y1[14] = fmaf(xb2, wD.z, y1[14]);
          y0[15] = fmaf(xa, wD.w, y0[15]);  y1[15] = fmaf(xb2, wD.w, y1[15]);
        }
      }
      // advance slice: kd step = HW; (c,2)->(c+1,0) step = (DD-2)*HW
      ps += (s == 2 || s == 5) ? (size_t)(DD - 2) * HW : (size_t)HW;
    }

#pragma unroll
    for (int oc = 0; oc < OCC; ++oc) {
      mn0[oc] = fminf(mn0[oc], y0[oc]);
      mn1[oc] = fminf(mn1[oc], y1[oc]);
    }
    xd += HW;  // next depth
  }

  // Stage 1: waves 4..7 publish partial mins into buffers 0..3.
  // Layout [oc][w] with lanes at w0=2*lane -> 2-way bank aliasing (free).
  if (g >= 4 && active) {
#pragma unroll
    for (int oc = 0; oc < OCC; ++oc) {
      sm[g - 4][oc][w0] = mn0[oc];
      sm[g - 4][oc][w0 + 1] = mn1[oc];
    }
  }
  __syncthreads();

  if (g < 4 && active) {
    // Wave g merges buffer g (each lane touches only its own columns, so the
    // stage-2 reuse of buffers 1..3 below is hazard-free).
#pragma unroll
    for (int oc = 0; oc < OCC; ++oc) {
      mn0[oc] = fminf(mn0[oc], sm[g][oc][w0]);
      mn1[oc] = fminf(mn1[oc], sm[g][oc][w0 + 1]);
    }
    // Stage 2: waves 1..3 publish merged mins into buffers 1..3.
    if (g > 0) {
#pragma unroll
      for (int oc = 0; oc < OCC; ++oc) {
        sm[g][oc][w0] = mn0[oc];
        sm[g][oc][w0 + 1] = mn1[oc];
      }
    }
  }
  __syncthreads();

  if (g == 0 && active) {
#pragma unroll
    for (int oc = 0; oc < OCC; ++oc) {
      mn0[oc] = fminf(fminf(mn0[oc], sm[1][oc][w0]),
                      fminf(sm[2][oc][w0], sm[3][oc][w0]));
      mn1[oc] = fminf(fminf(mn1[oc], sm[1][oc][w0 + 1]),
                      fminf(sm[2][oc][w0 + 1], sm[3][oc][w0 + 1]));
    }
    float mx0 = mn0[0], mx1 = mn1[0];
#pragma unroll
    for (int oc = 1; oc < OCC; ++oc) {
      mx0 = fmaxf(mx0, mn0[oc]);
      mx1 = fmaxf(mx1, mn1[oc]);
    }
    float e0[OCC], e1[OCC];
    float s0 = 0.f, s1 = 0.f;
#pragma unroll
    for (int oc = 0; oc < OCC; ++oc) {
      e0[oc] = __expf(mn0[oc] - mx0); s0 += e0[oc];
      e1[oc] = __expf(mn1[oc] - mx1); s1 += e1[oc];
    }
    const float i0 = 1.f / s0;
    const float i1 = 1.f / s1;

    float* ob = out + ((size_t)b * OCC * HOUT + h) * (size_t)WOUT + w0;
    const size_t os = (size_t)HOUT * WOUT;
#pragma unroll
    for (int oc = 0; oc < OCC; ++oc) {
      float2 v;
      v.x = e0[oc] * i0;
      v.y = e1[oc] * i1;
      *reinterpret_cast<float2*>(ob + oc * os) = v;  // w0 even -> 8B aligned
    }
  }
}

extern "C" void kernel_launch(void* const* d_in, const int* in_sizes, int n_in,
                              void* d_out, int out_size, void* d_ws, size_t ws_size,
                              hipStream_t stream) {
  const float* x = (const float*)d_in[0];
  const float* wt = (const float*)d_in[1];
  float* out = (float*)d_out;
  float* wT = (float*)d_ws;  // 81*16 floats = 5184 B scratch

  wtrans_kernel<<<dim3(6), dim3(256), 0, stream>>>(wt, wT);

  dim3 grid(1008);          // 1-D: wgid&7 = batch = XCD, wgid>>3 = h
  dim3 block(512, 1, 1);    // 8 waves = 8 dz-groups, Wtile=2
  conv_min_softmax_kernel<<<grid, block, 0, stream>>>(x, wT, out);
}